// Round 2
// baseline (258.863 us; speedup 1.0000x reference)
//
#include <hip/hip_runtime.h>

// Fused UnifiedQCNNKernelClassifier, round 2:
//  - S=4 samples/thread: amortize the ~736 scalar weight loads (SGPR traffic)
//    over 4 FMAs each, and force a sane register allocation (R1's VGPR=32
//    indicated heavy rematerialization).
//  - Rational (Eigen-style) tanh: 10 FMA + 1 v_rcp instead of v_exp + v_rcp;
//    cuts transcendental-pipe ops from 112/sample to ~59/sample.

constexpr int TPB = 256;
constexpr int S = 4;  // samples per thread

__device__ __forceinline__ float fexp(float x) {            // e^x
  return __builtin_amdgcn_exp2f(x * 1.4426950408889634f);
}

__device__ __forceinline__ float ftanh(float x) {
  // Rational minimax tanh (Eigen ptanh coefficients), clamp |x|<=7.9053.
  // abs err ~1e-7; 1 transcendental (v_rcp) instead of 2 (v_exp + v_rcp).
  const float xc = fminf(fmaxf(x, -7.90531110763549805f), 7.90531110763549805f);
  const float u = xc * xc;
  float p = -2.76076847742355e-16f;
  p = fmaf(p, u, 2.00018790482477e-13f);
  p = fmaf(p, u, -8.60467152213735e-11f);
  p = fmaf(p, u, 5.12229709037114e-08f);
  p = fmaf(p, u, 1.48572235717979e-05f);
  p = fmaf(p, u, 6.37261928875436e-04f);
  p = fmaf(p, u, 4.89352455891786e-03f);
  const float num = xc * p;
  float q = 1.19825839466702e-06f;
  q = fmaf(q, u, 1.18534705686654e-04f);
  q = fmaf(q, u, 2.26843463243900e-03f);
  q = fmaf(q, u, 4.89352518554385e-03f);
  return num * __builtin_amdgcn_rcpf(q);
}

template <int F, int G, bool DOTANH>
__device__ __forceinline__ void dense(const float* __restrict__ W,
                                      const float* __restrict__ b,
                                      const float (&in)[S][16],
                                      float (&out)[S][16]) {
#pragma unroll
  for (int j = 0; j < G; ++j) {
    float wr[F];
#pragma unroll
    for (int i = 0; i < F; ++i) wr[i] = W[j * F + i];  // uniform -> SGPR
    const float bj = b[j];
#pragma unroll
    for (int s = 0; s < S; ++s) {
      float acc = bj;
#pragma unroll
      for (int i = 0; i < F; ++i) acc = fmaf(in[s][i], wr[i], acc);
      out[s][j] = DOTANH ? ftanh(acc) : acc;
    }
  }
}

__global__ __launch_bounds__(TPB) void qcnn_fused(
    const float* __restrict__ x,
    const float* __restrict__ W1, const float* __restrict__ b1,
    const float* __restrict__ W2, const float* __restrict__ b2,
    const float* __restrict__ W3, const float* __restrict__ b3,
    const float* __restrict__ W4, const float* __restrict__ b4,
    const float* __restrict__ W5, const float* __restrict__ b5,
    const float* __restrict__ Wh, const float* __restrict__ bh,
    const float* __restrict__ Wf, const float* __restrict__ bf,
    const float* __restrict__ gammap,
    float* __restrict__ out, int n) {
  const int base = blockIdx.x * (TPB * S) + threadIdx.x;
  const float g = gammap[0];

  float h0[S][16], hA[S][16], hB[S][16];

#pragma unroll
  for (int s = 0; s < S; ++s) {
    const int smp = base + s * TPB;
    if (smp < n) {
      const float4* xp = reinterpret_cast<const float4*>(x) + (size_t)smp * 2;
      float4 a = xp[0];
      float4 c = xp[1];
      h0[s][0] = a.x; h0[s][1] = a.y; h0[s][2] = a.z; h0[s][3] = a.w;
      h0[s][4] = c.x; h0[s][5] = c.y; h0[s][6] = c.z; h0[s][7] = c.w;
    } else {
#pragma unroll
      for (int i = 0; i < 8; ++i) h0[s][i] = 0.0f;
    }
  }

  dense<8, 16, true>(W1, b1, h0, hA);
  dense<16, 16, true>(W2, b2, hA, hB);
  dense<16, 12, true>(W3, b3, hB, hA);
  dense<12, 8, true>(W4, b4, hA, hB);
  dense<8, 4, true>(W5, b5, hB, hA);
  dense<4, 4, false>(Wh, bh, hA, hB);  // cls_out in hB[s][0..3]

#pragma unroll
  for (int s = 0; s < S; ++s) {
    const int smp = base + s * TPB;
    if (smp >= n) continue;
    const float c0 = hB[s][0], c1 = hB[s][1], c2 = hB[s][2], c3 = hB[s][3];
    // qnn_out == 0 -> diff = cls_out; k = exp(-g * |cls|^2)
    const float ss = fmaf(c0, c0, fmaf(c1, c1, fmaf(c2, c2, c3 * c3)));
    const float k = fexp(-g * ss);
    // combined = [c0..c3, 0,0,0,0, k]; Wf is [2][9] row-major
    float o0 = bf[0];
    o0 = fmaf(Wf[0], c0, o0); o0 = fmaf(Wf[1], c1, o0);
    o0 = fmaf(Wf[2], c2, o0); o0 = fmaf(Wf[3], c3, o0);
    o0 = fmaf(Wf[8], k, o0);
    float o1 = bf[1];
    o1 = fmaf(Wf[9],  c0, o1); o1 = fmaf(Wf[10], c1, o1);
    o1 = fmaf(Wf[11], c2, o1); o1 = fmaf(Wf[12], c3, o1);
    o1 = fmaf(Wf[17], k, o1);
    // log_softmax over 2 classes
    const float m = fmaxf(o0, o1);
    const float sum = fexp(o0 - m) + fexp(o1 - m);
    const float lse = m + __builtin_amdgcn_logf(sum) * 0.6931471805599453f;
    float2 r;
    r.x = o0 - lse;
    r.y = o1 - lse;
    reinterpret_cast<float2*>(out)[smp] = r;
  }
}

extern "C" void kernel_launch(void* const* d_in, const int* in_sizes, int n_in,
                              void* d_out, int out_size, void* d_ws, size_t ws_size,
                              hipStream_t stream) {
  const float* x  = (const float*)d_in[0];
  const float* W1 = (const float*)d_in[1];
  const float* b1 = (const float*)d_in[2];
  const float* W2 = (const float*)d_in[3];
  const float* b2 = (const float*)d_in[4];
  const float* W3 = (const float*)d_in[5];
  const float* b3 = (const float*)d_in[6];
  const float* W4 = (const float*)d_in[7];
  const float* b4 = (const float*)d_in[8];
  const float* W5 = (const float*)d_in[9];
  const float* b5 = (const float*)d_in[10];
  const float* Wh = (const float*)d_in[11];
  const float* bh = (const float*)d_in[12];
  const float* Wf = (const float*)d_in[13];
  const float* bf = (const float*)d_in[14];
  const float* gm = (const float*)d_in[15];

  const int n = in_sizes[0] / 8;  // BATCH
  const int grid = (n + TPB * S - 1) / (TPB * S);
  qcnn_fused<<<grid, TPB, 0, stream>>>(x, W1, b1, W2, b2, W3, b3, W4, b4,
                                       W5, b5, Wh, bh, Wf, bf, gm,
                                       (float*)d_out, n);
}

// Round 5
// 190.782 us; speedup vs baseline: 1.3569x; 1.3569x over previous
//
#include <hip/hip_runtime.h>

// Fused UnifiedQCNNKernelClassifier, round 3 (2nd resubmit — GPU acquisition
// timed out twice; kernel unchanged, theory/predictions on record):
//   R1/R2 showed the compiler squeezing the kernel into 32-44 VGPRs to chase
//   8-waves/SIMD occupancy, serializing the FMA chains (latency-bound at
//   ~4cyc/FMA instead of issue-bound at 2). Fix: __launch_bounds__(TPB, 1)
//   frees the register allocator (up to arch cap); S=2 contiguous samples per
//   thread; rational tanh (1 v_rcp, no v_exp) kept from R2.

constexpr int TPB = 256;
constexpr int S = 2;  // samples per thread (contiguous)

__device__ __forceinline__ float fexp(float x) {            // e^x
  return __builtin_amdgcn_exp2f(x * 1.4426950408889634f);
}

__device__ __forceinline__ float ftanh(float x) {
  // Rational minimax tanh (Eigen ptanh coefficients), clamp |x|<=7.9053.
  const float xc = fminf(fmaxf(x, -7.90531110763549805f), 7.90531110763549805f);
  const float u = xc * xc;
  float p = -2.76076847742355e-16f;
  p = fmaf(p, u, 2.00018790482477e-13f);
  p = fmaf(p, u, -8.60467152213735e-11f);
  p = fmaf(p, u, 5.12229709037114e-08f);
  p = fmaf(p, u, 1.48572235717979e-05f);
  p = fmaf(p, u, 6.37261928875436e-04f);
  p = fmaf(p, u, 4.89352455891786e-03f);
  const float num = xc * p;
  float q = 1.19825839466702e-06f;
  q = fmaf(q, u, 1.18534705686654e-04f);
  q = fmaf(q, u, 2.26843463243900e-03f);
  q = fmaf(q, u, 4.89352518554385e-03f);
  return num * __builtin_amdgcn_rcpf(q);
}

template <int F, int G, bool DOTANH>
__device__ __forceinline__ void dense(const float* __restrict__ W,
                                      const float* __restrict__ b,
                                      const float (&in)[S][16],
                                      float (&out)[S][16]) {
#pragma unroll
  for (int j = 0; j < G; ++j) {
    float wr[F];
#pragma unroll
    for (int i = 0; i < F; ++i) wr[i] = W[j * F + i];  // uniform -> s_load
    const float bj = b[j];
#pragma unroll
    for (int s = 0; s < S; ++s) {
      float acc = bj;
#pragma unroll
      for (int i = 0; i < F; ++i) acc = fmaf(in[s][i], wr[i], acc);
      out[s][j] = DOTANH ? ftanh(acc) : acc;
    }
  }
}

__global__ __launch_bounds__(TPB, 1) void qcnn_fused(
    const float* __restrict__ x,
    const float* __restrict__ W1, const float* __restrict__ b1,
    const float* __restrict__ W2, const float* __restrict__ b2,
    const float* __restrict__ W3, const float* __restrict__ b3,
    const float* __restrict__ W4, const float* __restrict__ b4,
    const float* __restrict__ W5, const float* __restrict__ b5,
    const float* __restrict__ Wh, const float* __restrict__ bh,
    const float* __restrict__ Wf, const float* __restrict__ bf,
    const float* __restrict__ gammap,
    float* __restrict__ out, int n) {
  const int base = (blockIdx.x * TPB + threadIdx.x) * S;  // contiguous pair
  const float g = gammap[0];

  float h0[S][16], hA[S][16], hB[S][16];

  // x rows for samples [base, base+S) are 2*S float4s, contiguous.
#pragma unroll
  for (int s = 0; s < S; ++s) {
    const int smp = base + s;
    if (smp < n) {
      const float4* xp = reinterpret_cast<const float4*>(x) + (size_t)smp * 2;
      float4 a = xp[0];
      float4 c = xp[1];
      h0[s][0] = a.x; h0[s][1] = a.y; h0[s][2] = a.z; h0[s][3] = a.w;
      h0[s][4] = c.x; h0[s][5] = c.y; h0[s][6] = c.z; h0[s][7] = c.w;
    } else {
#pragma unroll
      for (int i = 0; i < 8; ++i) h0[s][i] = 0.0f;
    }
  }

  dense<8, 16, true>(W1, b1, h0, hA);
  dense<16, 16, true>(W2, b2, hA, hB);
  dense<16, 12, true>(W3, b3, hB, hA);
  dense<12, 8, true>(W4, b4, hA, hB);
  dense<8, 4, true>(W5, b5, hB, hA);
  dense<4, 4, false>(Wh, bh, hA, hB);  // cls_out in hB[s][0..3]

  float4 res[S / 2];  // pack two samples' (o0,o1) into one float4 store
  float tmp[S][2];

#pragma unroll
  for (int s = 0; s < S; ++s) {
    const float c0 = hB[s][0], c1 = hB[s][1], c2 = hB[s][2], c3 = hB[s][3];
    const float ss = fmaf(c0, c0, fmaf(c1, c1, fmaf(c2, c2, c3 * c3)));
    const float k = fexp(-g * ss);
    float o0 = bf[0];
    o0 = fmaf(Wf[0], c0, o0); o0 = fmaf(Wf[1], c1, o0);
    o0 = fmaf(Wf[2], c2, o0); o0 = fmaf(Wf[3], c3, o0);
    o0 = fmaf(Wf[8], k, o0);
    float o1 = bf[1];
    o1 = fmaf(Wf[9],  c0, o1); o1 = fmaf(Wf[10], c1, o1);
    o1 = fmaf(Wf[11], c2, o1); o1 = fmaf(Wf[12], c3, o1);
    o1 = fmaf(Wf[17], k, o1);
    const float m = fmaxf(o0, o1);
    const float sum = fexp(o0 - m) + fexp(o1 - m);
    const float lse = m + __builtin_amdgcn_logf(sum) * 0.6931471805599453f;
    tmp[s][0] = o0 - lse;
    tmp[s][1] = o1 - lse;
  }

  if (base + S <= n) {
#pragma unroll
    for (int p = 0; p < S / 2; ++p) {
      res[p].x = tmp[2 * p][0];
      res[p].y = tmp[2 * p][1];
      res[p].z = tmp[2 * p + 1][0];
      res[p].w = tmp[2 * p + 1][1];
      reinterpret_cast<float4*>(out)[base / 2 + p] = res[p];
    }
  } else {
#pragma unroll
    for (int s = 0; s < S; ++s) {
      if (base + s < n) {
        float2 r;
        r.x = tmp[s][0];
        r.y = tmp[s][1];
        reinterpret_cast<float2*>(out)[base + s] = r;
      }
    }
  }
}

extern "C" void kernel_launch(void* const* d_in, const int* in_sizes, int n_in,
                              void* d_out, int out_size, void* d_ws, size_t ws_size,
                              hipStream_t stream) {
  const float* x  = (const float*)d_in[0];
  const float* W1 = (const float*)d_in[1];
  const float* b1 = (const float*)d_in[2];
  const float* W2 = (const float*)d_in[3];
  const float* b2 = (const float*)d_in[4];
  const float* W3 = (const float*)d_in[5];
  const float* b3 = (const float*)d_in[6];
  const float* W4 = (const float*)d_in[7];
  const float* b4 = (const float*)d_in[8];
  const float* W5 = (const float*)d_in[9];
  const float* b5 = (const float*)d_in[10];
  const float* Wh = (const float*)d_in[11];
  const float* bh = (const float*)d_in[12];
  const float* Wf = (const float*)d_in[13];
  const float* bf = (const float*)d_in[14];
  const float* gm = (const float*)d_in[15];

  const int n = in_sizes[0] / 8;  // BATCH
  const int grid = (n + TPB * S - 1) / (TPB * S);
  qcnn_fused<<<grid, TPB, 0, stream>>>(x, W1, b1, W2, b2, W3, b3, W4, b4,
                                       W5, b5, Wh, bh, Wf, bf, gm,
                                       (float*)d_out, n);
}

// Round 8
// 173.194 us; speedup vs baseline: 1.4946x; 1.1015x over previous
//
#include <hip/hip_runtime.h>

// Fused UnifiedQCNNKernelClassifier, round 6 (3rd submit — two GPU acquisition
// timeouts; kernel unchanged): packed-FP32 (v_pk_fma_f32).
// R5 counters: VALUBusy ~100%, MfmaUtil 0, HBM 7% -> purely VALU-issue-bound.
// Lever: halve the issued-instruction count by packing the thread's two
// samples into <2 x float> and using elementwise fma/min/max builtins, which
// lower to VOP3P v_pk_fma_f32 / v_pk_max_f32 with op_sel broadcast of the
// SGPR-resident weight. tanh polynomial fully packed; rcp/exp stay scalar on
// the (idle) trans pipe. Clamp only on layer 1 (later pre-activations are
// bounded: |z| <= fan_in*|W|max + |b|max < 4.6 << 7.9).

typedef float v2f __attribute__((ext_vector_type(2)));

constexpr int TPB = 256;

__device__ __forceinline__ v2f splat(float v) {
  v2f r; r.x = v; r.y = v; return r;
}
__device__ __forceinline__ v2f vfma(v2f a, v2f b, v2f c) {
  return __builtin_elementwise_fma(a, b, c);
}
__device__ __forceinline__ float fexp(float x) {            // e^x
  return __builtin_amdgcn_exp2f(x * 1.4426950408889634f);
}

template <bool CLAMP>
__device__ __forceinline__ v2f ftanh2(v2f x) {
  // Rational minimax tanh (Eigen ptanh coefficients), packed over 2 samples.
  v2f xc = x;
  if (CLAMP) {
    xc = __builtin_elementwise_min(
        __builtin_elementwise_max(x, splat(-7.90531110763549805f)),
        splat(7.90531110763549805f));
  }
  const v2f u = xc * xc;
  v2f p = splat(-2.76076847742355e-16f);
  p = vfma(p, u, splat(2.00018790482477e-13f));
  p = vfma(p, u, splat(-8.60467152213735e-11f));
  p = vfma(p, u, splat(5.12229709037114e-08f));
  p = vfma(p, u, splat(1.48572235717979e-05f));
  p = vfma(p, u, splat(6.37261928875436e-04f));
  p = vfma(p, u, splat(4.89352455891786e-03f));
  const v2f num = xc * p;
  v2f q = splat(1.19825839466702e-06f);
  q = vfma(q, u, splat(1.18534705686654e-04f));
  q = vfma(q, u, splat(2.26843463243900e-03f));
  q = vfma(q, u, splat(4.89352518554385e-03f));
  v2f r;
  r.x = __builtin_amdgcn_rcpf(q.x);
  r.y = __builtin_amdgcn_rcpf(q.y);
  return num * r;
}

template <int F, int G, bool DOTANH, bool CLAMP>
__device__ __forceinline__ void dense(const float* __restrict__ W,
                                      const float* __restrict__ b,
                                      const v2f (&in)[16], v2f (&out)[16]) {
#pragma unroll
  for (int j = 0; j < G; ++j) {
    v2f acc = splat(b[j]);
#pragma unroll
    for (int i = 0; i < F; ++i)
      acc = vfma(in[i], splat(W[j * F + i]), acc);  // w uniform -> SGPR bcast
    out[j] = DOTANH ? ftanh2<CLAMP>(acc) : acc;
  }
}

__global__ __launch_bounds__(TPB) void qcnn_fused(
    const float* __restrict__ x,
    const float* __restrict__ W1, const float* __restrict__ b1,
    const float* __restrict__ W2, const float* __restrict__ b2,
    const float* __restrict__ W3, const float* __restrict__ b3,
    const float* __restrict__ W4, const float* __restrict__ b4,
    const float* __restrict__ W5, const float* __restrict__ b5,
    const float* __restrict__ Wh, const float* __restrict__ bh,
    const float* __restrict__ Wf, const float* __restrict__ bf,
    const float* __restrict__ gammap,
    float* __restrict__ out, int n) {
  const int base = (blockIdx.x * TPB + threadIdx.x) * 2;  // contiguous pair
  const float g = gammap[0];

  v2f h0[16], hA[16], hB[16];

  // Two contiguous rows of x (8 floats each) -> 4 float4 loads, pack to v2f.
  if (base + 1 < n) {
    const float4* xp = reinterpret_cast<const float4*>(x) + (size_t)base * 2;
    float4 a0 = xp[0], a1 = xp[1];  // sample base
    float4 c0 = xp[2], c1 = xp[3];  // sample base+1
    h0[0].x = a0.x; h0[0].y = c0.x;
    h0[1].x = a0.y; h0[1].y = c0.y;
    h0[2].x = a0.z; h0[2].y = c0.z;
    h0[3].x = a0.w; h0[3].y = c0.w;
    h0[4].x = a1.x; h0[4].y = c1.x;
    h0[5].x = a1.y; h0[5].y = c1.y;
    h0[6].x = a1.z; h0[6].y = c1.z;
    h0[7].x = a1.w; h0[7].y = c1.w;
  } else if (base < n) {  // n odd tail (not hit for BATCH=2^21)
    const float4* xp = reinterpret_cast<const float4*>(x) + (size_t)base * 2;
    float4 a0 = xp[0], a1 = xp[1];
    h0[0] = splat(a0.x); h0[1] = splat(a0.y);
    h0[2] = splat(a0.z); h0[3] = splat(a0.w);
    h0[4] = splat(a1.x); h0[5] = splat(a1.y);
    h0[6] = splat(a1.z); h0[7] = splat(a1.w);
  } else {
#pragma unroll
    for (int i = 0; i < 8; ++i) h0[i] = splat(0.0f);
  }

  dense<8, 16, true, true>(W1, b1, h0, hA);    // clamp needed (x unbounded)
  dense<16, 16, true, false>(W2, b2, hA, hB);  // |z| <= 4.25
  dense<16, 12, true, false>(W3, b3, hB, hA);  // |z| <= 4.25
  dense<12, 8, true, false>(W4, b4, hA, hB);   // |z| <= 3.75
  dense<8, 4, true, false>(W5, b5, hB, hA);    // |z| <= 3.18
  dense<4, 4, false, false>(Wh, bh, hA, hB);   // cls_out in hB[0..3]

  const v2f c0 = hB[0], c1 = hB[1], c2 = hB[2], c3 = hB[3];
  // qnn_out == 0 -> diff = cls_out; k = exp(-g * |cls|^2)
  const v2f ss = vfma(c0, c0, vfma(c1, c1, vfma(c2, c2, c3 * c3)));
  v2f k;
  k.x = fexp(-g * ss.x);
  k.y = fexp(-g * ss.y);
  // combined = [c0..c3, 0,0,0,0, k]; Wf is [2][9] row-major
  v2f o0 = splat(bf[0]);
  o0 = vfma(splat(Wf[0]), c0, o0);
  o0 = vfma(splat(Wf[1]), c1, o0);
  o0 = vfma(splat(Wf[2]), c2, o0);
  o0 = vfma(splat(Wf[3]), c3, o0);
  o0 = vfma(splat(Wf[8]), k, o0);
  v2f o1 = splat(bf[1]);
  o1 = vfma(splat(Wf[9]),  c0, o1);
  o1 = vfma(splat(Wf[10]), c1, o1);
  o1 = vfma(splat(Wf[11]), c2, o1);
  o1 = vfma(splat(Wf[12]), c3, o1);
  o1 = vfma(splat(Wf[17]), k, o1);
  // log_softmax over 2 classes, per sample
  const v2f m = __builtin_elementwise_max(o0, o1);
  const float s0 = fexp(o0.x - m.x) + fexp(o1.x - m.x);
  const float s1 = fexp(o0.y - m.y) + fexp(o1.y - m.y);
  const float lse0 = m.x + __builtin_amdgcn_logf(s0) * 0.6931471805599453f;
  const float lse1 = m.y + __builtin_amdgcn_logf(s1) * 0.6931471805599453f;

  if (base + 1 < n) {
    float4 r;
    r.x = o0.x - lse0;
    r.y = o1.x - lse0;
    r.z = o0.y - lse1;
    r.w = o1.y - lse1;
    reinterpret_cast<float4*>(out)[base / 2] = r;
  } else if (base < n) {
    float2 r;
    r.x = o0.x - lse0;
    r.y = o1.x - lse0;
    reinterpret_cast<float2*>(out)[base] = r;
  }
}

extern "C" void kernel_launch(void* const* d_in, const int* in_sizes, int n_in,
                              void* d_out, int out_size, void* d_ws, size_t ws_size,
                              hipStream_t stream) {
  const float* x  = (const float*)d_in[0];
  const float* W1 = (const float*)d_in[1];
  const float* b1 = (const float*)d_in[2];
  const float* W2 = (const float*)d_in[3];
  const float* b2 = (const float*)d_in[4];
  const float* W3 = (const float*)d_in[5];
  const float* b3 = (const float*)d_in[6];
  const float* W4 = (const float*)d_in[7];
  const float* b4 = (const float*)d_in[8];
  const float* W5 = (const float*)d_in[9];
  const float* b5 = (const float*)d_in[10];
  const float* Wh = (const float*)d_in[11];
  const float* bh = (const float*)d_in[12];
  const float* Wf = (const float*)d_in[13];
  const float* bf = (const float*)d_in[14];
  const float* gm = (const float*)d_in[15];

  const int n = in_sizes[0] / 8;  // BATCH
  const int grid = (n + TPB * 2 - 1) / (TPB * 2);
  qcnn_fused<<<grid, TPB, 0, stream>>>(x, W1, b1, W2, b2, W3, b3, W4, b4,
                                       W5, b5, Wh, bh, Wf, bf, gm,
                                       (float*)d_out, n);
}

// Round 10
// 159.491 us; speedup vs baseline: 1.6231x; 1.0859x over previous
//
#include <hip/hip_runtime.h>

// Fused UnifiedQCNNKernelClassifier, round 9 (resubmit — GPU acquisition
// timeout; kernel unchanged): trans-pipe tanh.
// R8: packed fp32 -> 73.6us, VALUBusy 68% (was 100%). pk ops are 2-pass on
// CDNA4 (no fp32 packed doubling) -> we sit at ~49% of the 157TF fp32
// roofline, VALU-issue-bound, trans pipe ~25% and partially overlapped.
// Lever: rational tanh spends 12 pk-ops (48 VALU cyc) per packed pair to
// avoid the trans pipe. Exp-form tanh = 1 - 2*rcp(exp2(2x*log2e)+1) is
// 3 pk-ops + 4 trans: moves ~2000 cyc/wave from the saturated VALU pipe to
// the idle trans unit. Exact (no poly error), inf-safe (rcp(inf)=0 gives
// +/-1), so the layer-1 clamp disappears too.

typedef float v2f __attribute__((ext_vector_type(2)));

constexpr int TPB = 256;

__device__ __forceinline__ v2f splat(float v) {
  v2f r; r.x = v; r.y = v; return r;
}
__device__ __forceinline__ v2f vfma(v2f a, v2f b, v2f c) {
  return __builtin_elementwise_fma(a, b, c);
}
__device__ __forceinline__ float fexp(float x) {            // e^x
  return __builtin_amdgcn_exp2f(x * 1.4426950408889634f);
}

__device__ __forceinline__ v2f ftanh2(v2f x) {
  // tanh(x) = 1 - 2/(e^{2x}+1), packed over 2 samples.
  // VALU: 1 pk_mul + 1 pk_add + 1 pk_fma; trans: 2 exp2 + 2 rcp.
  // x->+inf: exp2->inf, rcp->0, res=1. x->-inf: exp2->0, res=-1. No clamp.
  const v2f t = x * splat(2.8853900817779268f);  // 2*log2(e)
  v2f e;
  e.x = __builtin_amdgcn_exp2f(t.x);
  e.y = __builtin_amdgcn_exp2f(t.y);
  const v2f d = e + splat(1.0f);
  v2f r;
  r.x = __builtin_amdgcn_rcpf(d.x);
  r.y = __builtin_amdgcn_rcpf(d.y);
  return vfma(splat(-2.0f), r, splat(1.0f));
}

template <int F, int G, bool DOTANH>
__device__ __forceinline__ void dense(const float* __restrict__ W,
                                      const float* __restrict__ b,
                                      const v2f (&in)[16], v2f (&out)[16]) {
#pragma unroll
  for (int j = 0; j < G; ++j) {
    v2f acc = splat(b[j]);
#pragma unroll
    for (int i = 0; i < F; ++i)
      acc = vfma(in[i], splat(W[j * F + i]), acc);  // w uniform -> SGPR bcast
    out[j] = DOTANH ? ftanh2(acc) : acc;
  }
}

__global__ __launch_bounds__(TPB) void qcnn_fused(
    const float* __restrict__ x,
    const float* __restrict__ W1, const float* __restrict__ b1,
    const float* __restrict__ W2, const float* __restrict__ b2,
    const float* __restrict__ W3, const float* __restrict__ b3,
    const float* __restrict__ W4, const float* __restrict__ b4,
    const float* __restrict__ W5, const float* __restrict__ b5,
    const float* __restrict__ Wh, const float* __restrict__ bh,
    const float* __restrict__ Wf, const float* __restrict__ bf,
    const float* __restrict__ gammap,
    float* __restrict__ out, int n) {
  const int base = (blockIdx.x * TPB + threadIdx.x) * 2;  // contiguous pair
  const float g = gammap[0];

  v2f h0[16], hA[16], hB[16];

  // Two contiguous rows of x (8 floats each) -> 4 float4 loads, pack to v2f.
  if (base + 1 < n) {
    const float4* xp = reinterpret_cast<const float4*>(x) + (size_t)base * 2;
    float4 a0 = xp[0], a1 = xp[1];  // sample base
    float4 c0 = xp[2], c1 = xp[3];  // sample base+1
    h0[0].x = a0.x; h0[0].y = c0.x;
    h0[1].x = a0.y; h0[1].y = c0.y;
    h0[2].x = a0.z; h0[2].y = c0.z;
    h0[3].x = a0.w; h0[3].y = c0.w;
    h0[4].x = a1.x; h0[4].y = c1.x;
    h0[5].x = a1.y; h0[5].y = c1.y;
    h0[6].x = a1.z; h0[6].y = c1.z;
    h0[7].x = a1.w; h0[7].y = c1.w;
  } else if (base < n) {  // n odd tail (not hit for BATCH=2^21)
    const float4* xp = reinterpret_cast<const float4*>(x) + (size_t)base * 2;
    float4 a0 = xp[0], a1 = xp[1];
    h0[0] = splat(a0.x); h0[1] = splat(a0.y);
    h0[2] = splat(a0.z); h0[3] = splat(a0.w);
    h0[4] = splat(a1.x); h0[5] = splat(a1.y);
    h0[6] = splat(a1.z); h0[7] = splat(a1.w);
  } else {
#pragma unroll
    for (int i = 0; i < 8; ++i) h0[i] = splat(0.0f);
  }

  dense<8, 16, true>(W1, b1, h0, hA);
  dense<16, 16, true>(W2, b2, hA, hB);
  dense<16, 12, true>(W3, b3, hB, hA);
  dense<12, 8, true>(W4, b4, hA, hB);
  dense<8, 4, true>(W5, b5, hB, hA);
  dense<4, 4, false>(Wh, bh, hA, hB);  // cls_out in hB[0..3]

  const v2f c0 = hB[0], c1 = hB[1], c2 = hB[2], c3 = hB[3];
  // qnn_out == 0 -> diff = cls_out; k = exp(-g * |cls|^2)
  const v2f ss = vfma(c0, c0, vfma(c1, c1, vfma(c2, c2, c3 * c3)));
  v2f k;
  k.x = fexp(-g * ss.x);
  k.y = fexp(-g * ss.y);
  // combined = [c0..c3, 0,0,0,0, k]; Wf is [2][9] row-major
  v2f o0 = splat(bf[0]);
  o0 = vfma(splat(Wf[0]), c0, o0);
  o0 = vfma(splat(Wf[1]), c1, o0);
  o0 = vfma(splat(Wf[2]), c2, o0);
  o0 = vfma(splat(Wf[3]), c3, o0);
  o0 = vfma(splat(Wf[8]), k, o0);
  v2f o1 = splat(bf[1]);
  o1 = vfma(splat(Wf[9]),  c0, o1);
  o1 = vfma(splat(Wf[10]), c1, o1);
  o1 = vfma(splat(Wf[11]), c2, o1);
  o1 = vfma(splat(Wf[12]), c3, o1);
  o1 = vfma(splat(Wf[17]), k, o1);
  // log_softmax over 2 classes, per sample
  const v2f m = __builtin_elementwise_max(o0, o1);
  const float s0 = fexp(o0.x - m.x) + fexp(o1.x - m.x);
  const float s1 = fexp(o0.y - m.y) + fexp(o1.y - m.y);
  const float lse0 = m.x + __builtin_amdgcn_logf(s0) * 0.6931471805599453f;
  const float lse1 = m.y + __builtin_amdgcn_logf(s1) * 0.6931471805599453f;

  if (base + 1 < n) {
    float4 r;
    r.x = o0.x - lse0;
    r.y = o1.x - lse0;
    r.z = o0.y - lse1;
    r.w = o1.y - lse1;
    reinterpret_cast<float4*>(out)[base / 2] = r;
  } else if (base < n) {
    float2 r;
    r.x = o0.x - lse0;
    r.y = o1.x - lse0;
    reinterpret_cast<float2*>(out)[base] = r;
  }
}

extern "C" void kernel_launch(void* const* d_in, const int* in_sizes, int n_in,
                              void* d_out, int out_size, void* d_ws, size_t ws_size,
                              hipStream_t stream) {
  const float* x  = (const float*)d_in[0];
  const float* W1 = (const float*)d_in[1];
  const float* b1 = (const float*)d_in[2];
  const float* W2 = (const float*)d_in[3];
  const float* b2 = (const float*)d_in[4];
  const float* W3 = (const float*)d_in[5];
  const float* b3 = (const float*)d_in[6];
  const float* W4 = (const float*)d_in[7];
  const float* b4 = (const float*)d_in[8];
  const float* W5 = (const float*)d_in[9];
  const float* b5 = (const float*)d_in[10];
  const float* Wh = (const float*)d_in[11];
  const float* bh = (const float*)d_in[12];
  const float* Wf = (const float*)d_in[13];
  const float* bf = (const float*)d_in[14];
  const float* gm = (const float*)d_in[15];

  const int n = in_sizes[0] / 8;  // BATCH
  const int grid = (n + TPB * 2 - 1) / (TPB * 2);
  qcnn_fused<<<grid, TPB, 0, stream>>>(x, W1, b1, W2, b2, W3, b3, W4, b4,
                                       W5, b5, Wh, bh, Wf, bf, gm,
                                       (float*)d_out, n);
}